// Round 1
// baseline (1655.759 us; speedup 1.0000x reference)
//
#include <hip/hip_runtime.h>
#include <hip/hip_bf16.h>

#define B_ 2
#define C_ 64
#define L_ 16
#define H_ 64
#define W_ 64
#define N_ 32      // B*L
#define HW_ 4096
#define NG_ 4

// ws layout (floats)
#define OFF_WEFF 0
#define SZ_WEFF (49*64*64)            // 200704
#define OFF_Y   (OFF_WEFF + SZ_WEFF)
#define SZ_Y    (N_*HW_*C_)           // 8388608
#define OFF_ST  (OFF_Y + SZ_Y)
#define SZ_ST   (N_*NG_*2)
#define OFF_LR  (OFF_ST + SZ_ST)
#define OFF_LI  (OFF_LR + N_*C_)
#define OFF_GM  (OFF_LI + N_*C_)

// ---------------- fold W_dc into W_sp: W_eff[i][tap][o] ----------------
__global__ void k_fold(const float* __restrict__ W_sp, const float* __restrict__ W_dc,
                       float* __restrict__ W_eff) {
    int idx = blockIdx.x * 256 + threadIdx.x;
    if (idx >= 49 * 64 * 64) return;
    int o = idx & 63;
    int t = (idx >> 6) % 49;
    int i = idx / (49 * 64);
    float s = 0.f;
    for (int c = 0; c < 64; ++c)
        s += W_dc[o * 64 + c] * W_sp[(c * 64 + i) * 49 + t];
    W_eff[idx] = s;
}

// ---------------- lambda tables per (n=b*L+l, c) ----------------
__global__ void k_lam(const float* __restrict__ dt, const float* __restrict__ nu_log,
                      const float* __restrict__ theta_log,
                      float* __restrict__ lr_t, float* __restrict__ li_t, float* __restrict__ gm_t) {
    int idx = blockIdx.x * 256 + threadIdx.x;
    if (idx >= N_ * C_) return;
    int c = idx & 63, n = idx >> 6;
    float dtv = dt[n];                       // dt[b][l], n = b*16+l
    float decay = expf(-expf(nu_log[c]) * dtv);
    float phase = expf(theta_log[c]) * dtv;
    lr_t[idx] = decay * cosf(phase);
    li_t[idx] = decay * sinf(phase);
    gm_t[idx] = sqrtf(fmaxf(1.f - decay * decay, 1e-6f));
}

// ---------------- 7x7 conv with folded weights, wrap-W / edge-H ----------------
// grid: (16 tiles, 4 oc-groups, 32 n). block 256.
// thread: 4 consecutive w-pixels x 4 consecutive ocs.
__global__ __launch_bounds__(256) void k_conv(
    const float* __restrict__ x, const float* __restrict__ W_eff,
    const float* __restrict__ b_dc, float* __restrict__ y) {
    __shared__ __align__(16) float xs[4][22][24];   // 4 ic, 22 rows, 22 cols (stride 24)
    __shared__ __align__(16) float wl[4][49][16];   // 4 ic, 49 taps, 16 ocs
    int tid = threadIdx.x;
    int tile = blockIdx.x;
    int th = tile >> 2, tw = tile & 3;
    int ocb = blockIdx.y * 16;
    int n = blockIdx.z;
    int b = n >> 4, l = n & 15;
    int q4  = (tid & 3) * 4;        // w offset within 16-wide tile
    int r   = (tid >> 2) & 15;      // h row within tile
    int og4 = (tid >> 6) * 4;       // oc offset within 16-oc group

    float acc[4][4] = {};

    for (int cb = 0; cb < 64; cb += 4) {
        // stage input tile (4 ic x 22 x 22), edge-clamped H, wrapped W
        for (int e = tid; e < 4 * 22 * 22; e += 256) {
            int ic = e / 484, rem = e - ic * 484;
            int row = rem / 22, col = rem - row * 22;
            int hs = th * 16 + row - 3; hs = hs < 0 ? 0 : (hs > 63 ? 63 : hs);
            int wsv = (tw * 16 + col - 3) & 63;
            xs[ic][row][col] = x[((b * 64 + cb + ic) * 16 + l) * 4096 + hs * 64 + wsv];
        }
        // stage weights (4 ic x 49 taps x 16 ocs)
        for (int e = tid; e < 4 * 49 * 16; e += 256) {
            int ic = e / 784, rem = e - ic * 784;
            int t = rem >> 4, j = rem & 15;
            wl[ic][t][j] = W_eff[((cb + ic) * 49 + t) * 64 + ocb + j];
        }
        __syncthreads();

        #pragma unroll
        for (int ic = 0; ic < 4; ++ic) {
            #pragma unroll
            for (int kh = 0; kh < 7; ++kh) {
                const float* xp = &xs[ic][r + kh][q4];
                float4 xa = *(const float4*)xp;
                float4 xb = *(const float4*)(xp + 4);
                float4 xc = *(const float4*)(xp + 8);
                float xr[12];
                xr[0]=xa.x; xr[1]=xa.y; xr[2]=xa.z; xr[3]=xa.w;
                xr[4]=xb.x; xr[5]=xb.y; xr[6]=xb.z; xr[7]=xb.w;
                xr[8]=xc.x; xr[9]=xc.y; xr[10]=xc.z; xr[11]=xc.w;
                #pragma unroll
                for (int kw = 0; kw < 7; ++kw) {
                    float4 w4 = *(const float4*)&wl[ic][kh * 7 + kw][og4];
                    #pragma unroll
                    for (int p = 0; p < 4; ++p) {
                        float xv = xr[p + kw];
                        acc[p][0] += xv * w4.x;
                        acc[p][1] += xv * w4.y;
                        acc[p][2] += xv * w4.z;
                        acc[p][3] += xv * w4.w;
                    }
                }
            }
        }
        __syncthreads();
    }

    int oc0 = ocb + og4;
    float4 bv = *(const float4*)&b_dc[oc0];
    int hh = th * 16 + r;
    #pragma unroll
    for (int p = 0; p < 4; ++p) {
        int ww = tw * 16 + q4 + p;
        float4 st;
        st.x = acc[p][0] + bv.x; st.y = acc[p][1] + bv.y;
        st.z = acc[p][2] + bv.z; st.w = acc[p][3] + bv.w;
        *(float4*)&y[(n * 4096 + hh * 64 + ww) * 64 + oc0] = st;
    }
}

// ---------------- GroupNorm stats per (n, g) ----------------
__global__ void k_gnstats(const float* __restrict__ y, float* __restrict__ stats) {
    int bid = blockIdx.x;          // n*4+g
    int n = bid >> 2, g = bid & 3;
    int tid = threadIdx.x;
    int c = g * 16 + (tid & 15);
    float s = 0.f, s2 = 0.f;
    for (int p = (tid >> 4); p < 4096; p += 16) {
        float v = y[(n * 4096 + p) * 64 + c];
        s += v; s2 += v * v;
    }
    __shared__ float rs[256], rq[256];
    rs[tid] = s; rq[tid] = s2;
    __syncthreads();
    for (int off = 128; off; off >>= 1) {
        if (tid < off) { rs[tid] += rs[tid + off]; rq[tid] += rq[tid + off]; }
        __syncthreads();
    }
    if (tid == 0) {
        float mean = rs[0] * (1.f / 65536.f);
        float var  = rq[0] * (1.f / 65536.f) - mean * mean;
        stats[bid * 2]     = mean;
        stats[bid * 2 + 1] = rsqrtf(var + 1e-5f);
    }
}

// ---------------- GN-apply + W_in + GLU + W_out + residual (in-place y->u) ----------------
// grid: 32 n * 64 pixel-groups. block 256. 64 pixels per block.
__global__ __launch_bounds__(256) void k_pw(
    const float* __restrict__ y, const float* __restrict__ stats,
    const float* __restrict__ gn_g, const float* __restrict__ gn_b,
    const float* __restrict__ W_in, const float* __restrict__ b_in,
    const float* __restrict__ W_out, const float* __restrict__ b_out,
    const float* __restrict__ x, float* __restrict__ u) {
    __shared__ float yn[64][65];
    __shared__ float hb[64][130];
    int tid = threadIdx.x;
    int n = blockIdx.x >> 6, pg = blockIdx.x & 63;
    int p0 = pg * 64;
    int b = n >> 4, l = n & 15;

    // phase 0: load y, apply GN
    for (int k = 0; k < 16; ++k) {
        int idx = k * 256 + tid;
        int pix = idx >> 6, c = idx & 63, g = c >> 4;
        float mean = stats[(n * 4 + g) * 2];
        float rstd = stats[(n * 4 + g) * 2 + 1];
        float v = y[(n * 4096 + p0 + pix) * 64 + c];
        yn[pix][c] = (v - mean) * rstd * gn_g[c] + gn_b[c];
    }
    __syncthreads();

    // phase 1: h = W_in * yn + b_in  (128 outputs per pixel)
    {
        int p = tid >> 2, ob = (tid & 3) * 32;
        float acc[32];
        #pragma unroll
        for (int j = 0; j < 32; ++j) acc[j] = b_in[ob + j];
        for (int c = 0; c < 64; ++c) {
            float yv = yn[p][c];
            #pragma unroll
            for (int j = 0; j < 32; ++j)
                acc[j] += W_in[(ob + j) * 64 + c] * yv;
        }
        #pragma unroll
        for (int j = 0; j < 32; ++j) hb[p][ob + j] = acc[j];
    }
    __syncthreads();

    // phase 2: z = x1 * sigmoid(x2) -> yn
    for (int k = 0; k < 16; ++k) {
        int idx = k * 256 + tid;
        int pix = idx >> 6, c = idx & 63;
        float x1 = hb[pix][c], x2 = hb[pix][64 + c];
        yn[pix][c] = x1 / (1.f + expf(-x2));
    }
    __syncthreads();

    // phase 3: u = W_out * z + b_out + xf   (in-place over y)
    {
        int p = tid >> 2, ob = (tid & 3) * 16;
        float acc[16];
        #pragma unroll
        for (int j = 0; j < 16; ++j) acc[j] = b_out[ob + j];
        for (int c = 0; c < 64; ++c) {
            float zv = yn[p][c];
            #pragma unroll
            for (int j = 0; j < 16; ++j)
                acc[j] += W_out[(ob + j) * 64 + c] * zv;
        }
        int pp = p0 + p;
        #pragma unroll
        for (int j = 0; j < 16; ++j) {
            float xf = x[((b * 64 + ob + j) * 16 + l) * 4096 + pp];
            u[(n * 4096 + pp) * 64 + ob + j] = acc[j] + xf;
        }
    }
}

// ---------------- LRU scan over l, output (B,C,L,H,W) ----------------
// grid: b*h = 128 blocks. block 256: lanes = w, thread holds 16 (c) states.
__global__ __launch_bounds__(256) void k_scan(
    const float* __restrict__ u, const float* __restrict__ lr_t,
    const float* __restrict__ li_t, const float* __restrict__ gm_t,
    const float* __restrict__ c_re, const float* __restrict__ c_im,
    const float* __restrict__ d_skip, float* __restrict__ out) {
    __shared__ float us[64][65];
    int tid = threadIdx.x;
    int b = blockIdx.x >> 6, h = blockIdx.x & 63;
    int w = tid & 63;
    int cg = tid >> 6;            // 0..3
    float hr[16] = {}, hi[16] = {};
    for (int l = 0; l < 16; ++l) {
        int n = b * 16 + l;
        const float* ub = &u[(n * 4096 + h * 64) * 64];
        for (int k = 0; k < 16; ++k) {
            int idx = k * 256 + tid;
            us[idx >> 6][idx & 63] = ub[idx];   // us[w][c]
        }
        __syncthreads();
        #pragma unroll
        for (int e = 0; e < 16; ++e) {
            int c = e * 4 + cg;
            float ut = us[w][c];
            float lr = lr_t[n * 64 + c], li = li_t[n * 64 + c], gm = gm_t[n * 64 + c];
            float nr = lr * hr[e] - li * hi[e] + gm * ut;
            float ni = li * hr[e] + lr * hi[e];
            float yv = c_re[c] * nr + c_im[c] * ni + d_skip[c] * ut;
            hr[e] = nr; hi[e] = ni;
            out[((b * 64 + c) * 16 + l) * 4096 + h * 64 + w] = yv;
        }
        __syncthreads();
    }
}

extern "C" void kernel_launch(void* const* d_in, const int* in_sizes, int n_in,
                              void* d_out, int out_size, void* d_ws, size_t ws_size,
                              hipStream_t stream) {
    const float* x        = (const float*)d_in[0];
    const float* dt       = (const float*)d_in[1];
    const float* W_sp     = (const float*)d_in[2];
    const float* W_dc     = (const float*)d_in[3];
    const float* b_dc     = (const float*)d_in[4];
    const float* gn_g     = (const float*)d_in[5];
    const float* gn_b     = (const float*)d_in[6];
    const float* W_in     = (const float*)d_in[7];
    const float* b_in     = (const float*)d_in[8];
    const float* W_out    = (const float*)d_in[9];
    const float* b_out    = (const float*)d_in[10];
    const float* nu_log   = (const float*)d_in[11];
    const float* theta_log= (const float*)d_in[12];
    const float* c_re     = (const float*)d_in[13];
    const float* c_im     = (const float*)d_in[14];
    const float* d_skip   = (const float*)d_in[15];

    float* ws    = (float*)d_ws;
    float* W_eff = ws + OFF_WEFF;
    float* y     = ws + OFF_Y;     // reused in-place as u by k_pw
    float* stats = ws + OFF_ST;
    float* lr_t  = ws + OFF_LR;
    float* li_t  = ws + OFF_LI;
    float* gm_t  = ws + OFF_GM;
    float* out   = (float*)d_out;

    hipLaunchKernelGGL(k_fold,    dim3(784),      dim3(256), 0, stream, W_sp, W_dc, W_eff);
    hipLaunchKernelGGL(k_lam,     dim3(8),        dim3(256), 0, stream, dt, nu_log, theta_log, lr_t, li_t, gm_t);
    hipLaunchKernelGGL(k_conv,    dim3(16, 4, 32),dim3(256), 0, stream, x, W_eff, b_dc, y);
    hipLaunchKernelGGL(k_gnstats, dim3(128),      dim3(256), 0, stream, y, stats);
    hipLaunchKernelGGL(k_pw,      dim3(2048),     dim3(256), 0, stream, y, stats, gn_g, gn_b,
                       W_in, b_in, W_out, b_out, x, y);
    hipLaunchKernelGGL(k_scan,    dim3(128),      dim3(256), 0, stream, y, lr_t, li_t, gm_t,
                       c_re, c_im, d_skip, out);
}

// Round 2
// 887.550 us; speedup vs baseline: 1.8655x; 1.8655x over previous
//
#include <hip/hip_runtime.h>
#include <hip/hip_bf16.h>

#define B_ 2
#define C_ 64
#define L_ 16
#define H_ 64
#define W_ 64
#define N_ 32      // B*L
#define HW_ 4096
#define NG_ 4

// ws layout (floats)
#define OFF_WEFF 0
#define SZ_WEFF (49*64*64)            // 200704
#define OFF_Y   (OFF_WEFF + SZ_WEFF)
#define SZ_Y    (N_*HW_*C_)           // 8388608
#define OFF_ST  (OFF_Y + SZ_Y)
#define SZ_ST   (N_*NG_*2)
#define OFF_LR  (OFF_ST + SZ_ST)
#define OFF_LI  (OFF_LR + N_*C_)
#define OFF_GM  (OFF_LI + N_*C_)
#define OFF_WOT (OFF_GM + N_*C_)
#define SZ_WOT  (64*64)

// ---------------- fold W_dc into W_sp: W_eff[i][tap][o] ----------------
__global__ void k_fold(const float* __restrict__ W_sp, const float* __restrict__ W_dc,
                       float* __restrict__ W_eff) {
    int idx = blockIdx.x * 256 + threadIdx.x;
    if (idx >= 49 * 64 * 64) return;
    int o = idx & 63;
    int t = (idx >> 6) % 49;
    int i = idx / (49 * 64);
    float s = 0.f;
    for (int c = 0; c < 64; ++c)
        s += W_dc[o * 64 + c] * W_sp[(c * 64 + i) * 49 + t];
    W_eff[idx] = s;
}

// ---------------- transpose W_out: W_outT[o][j] = W_out[j][o] ----------------
__global__ void k_wot(const float* __restrict__ W_out, float* __restrict__ W_outT) {
    int idx = blockIdx.x * 256 + threadIdx.x;
    if (idx >= 64 * 64) return;
    int o = idx >> 6, j = idx & 63;
    W_outT[o * 64 + j] = W_out[j * 64 + o];
}

// ---------------- lambda tables per (n=b*L+l, c) ----------------
__global__ void k_lam(const float* __restrict__ dt, const float* __restrict__ nu_log,
                      const float* __restrict__ theta_log,
                      float* __restrict__ lr_t, float* __restrict__ li_t, float* __restrict__ gm_t) {
    int idx = blockIdx.x * 256 + threadIdx.x;
    if (idx >= N_ * C_) return;
    int c = idx & 63, n = idx >> 6;
    float dtv = dt[n];                       // dt[b][l], n = b*16+l
    float decay = expf(-expf(nu_log[c]) * dtv);
    float phase = expf(theta_log[c]) * dtv;
    lr_t[idx] = decay * cosf(phase);
    li_t[idx] = decay * sinf(phase);
    gm_t[idx] = sqrtf(fmaxf(1.f - decay * decay, 1e-6f));
}

// ---------------- 7x7 conv with folded weights, wrap-W / edge-H ----------------
// grid: (16 tiles, 4 oc-groups, 32 n). block 256.
// thread: 4 consecutive w-pixels x 4 consecutive ocs.
__global__ __launch_bounds__(256) void k_conv(
    const float* __restrict__ x, const float* __restrict__ W_eff,
    const float* __restrict__ b_dc, float* __restrict__ y) {
    __shared__ __align__(16) float xs[4][22][24];   // 4 ic, 22 rows, 22 cols (stride 24)
    __shared__ __align__(16) float wl[4][49][16];   // 4 ic, 49 taps, 16 ocs
    int tid = threadIdx.x;
    int tile = blockIdx.x;
    int th = tile >> 2, tw = tile & 3;
    int ocb = blockIdx.y * 16;
    int n = blockIdx.z;
    int b = n >> 4, l = n & 15;
    int q4  = (tid & 3) * 4;        // w offset within 16-wide tile
    int r   = (tid >> 2) & 15;      // h row within tile
    int og4 = (tid >> 6) * 4;       // oc offset within 16-oc group

    float acc[4][4] = {};

    for (int cb = 0; cb < 64; cb += 4) {
        // stage input tile (4 ic x 22 x 22), edge-clamped H, wrapped W
        for (int e = tid; e < 4 * 22 * 22; e += 256) {
            int ic = e / 484, rem = e - ic * 484;
            int row = rem / 22, col = rem - row * 22;
            int hs = th * 16 + row - 3; hs = hs < 0 ? 0 : (hs > 63 ? 63 : hs);
            int wsv = (tw * 16 + col - 3) & 63;
            xs[ic][row][col] = x[((b * 64 + cb + ic) * 16 + l) * 4096 + hs * 64 + wsv];
        }
        // stage weights (4 ic x 49 taps x 16 ocs)
        for (int e = tid; e < 4 * 49 * 16; e += 256) {
            int ic = e / 784, rem = e - ic * 784;
            int t = rem >> 4, j = rem & 15;
            wl[ic][t][j] = W_eff[((cb + ic) * 49 + t) * 64 + ocb + j];
        }
        __syncthreads();

        #pragma unroll
        for (int ic = 0; ic < 4; ++ic) {
            #pragma unroll
            for (int kh = 0; kh < 7; ++kh) {
                const float* xp = &xs[ic][r + kh][q4];
                float4 xa = *(const float4*)xp;
                float4 xb = *(const float4*)(xp + 4);
                float4 xc = *(const float4*)(xp + 8);
                float xr[12];
                xr[0]=xa.x; xr[1]=xa.y; xr[2]=xa.z; xr[3]=xa.w;
                xr[4]=xb.x; xr[5]=xb.y; xr[6]=xb.z; xr[7]=xb.w;
                xr[8]=xc.x; xr[9]=xc.y; xr[10]=xc.z; xr[11]=xc.w;
                #pragma unroll
                for (int kw = 0; kw < 7; ++kw) {
                    float4 w4 = *(const float4*)&wl[ic][kh * 7 + kw][og4];
                    #pragma unroll
                    for (int p = 0; p < 4; ++p) {
                        float xv = xr[p + kw];
                        acc[p][0] += xv * w4.x;
                        acc[p][1] += xv * w4.y;
                        acc[p][2] += xv * w4.z;
                        acc[p][3] += xv * w4.w;
                    }
                }
            }
        }
        __syncthreads();
    }

    int oc0 = ocb + og4;
    float4 bv = *(const float4*)&b_dc[oc0];
    int hh = th * 16 + r;
    #pragma unroll
    for (int p = 0; p < 4; ++p) {
        int ww = tw * 16 + q4 + p;
        float4 st;
        st.x = acc[p][0] + bv.x; st.y = acc[p][1] + bv.y;
        st.z = acc[p][2] + bv.z; st.w = acc[p][3] + bv.w;
        *(float4*)&y[(n * 4096 + hh * 64 + ww) * 64 + oc0] = st;
    }
}

// ---------------- GroupNorm stats per (n, g) ----------------
__global__ void k_gnstats(const float* __restrict__ y, float* __restrict__ stats) {
    int bid = blockIdx.x;          // n*4+g
    int n = bid >> 2, g = bid & 3;
    int tid = threadIdx.x;
    int c = g * 16 + (tid & 15);
    float s = 0.f, s2 = 0.f;
    for (int p = (tid >> 4); p < 4096; p += 16) {
        float v = y[(n * 4096 + p) * 64 + c];
        s += v; s2 += v * v;
    }
    __shared__ float rs[256], rq[256];
    rs[tid] = s; rq[tid] = s2;
    __syncthreads();
    for (int off = 128; off; off >>= 1) {
        if (tid < off) { rs[tid] += rs[tid + off]; rq[tid] += rq[tid + off]; }
        __syncthreads();
    }
    if (tid == 0) {
        float mean = rs[0] * (1.f / 65536.f);
        float var  = rq[0] * (1.f / 65536.f) - mean * mean;
        stats[bid * 2]     = mean;
        stats[bid * 2 + 1] = rsqrtf(var + 1e-5f);
    }
}

// ---------------- GN-apply + W_in + GLU + W_out + residual (in-place y->u) ----------------
// lane = pixel; weights via wave-uniform scalar loads; yn & u-acc in VGPRs.
// grid: 512 blocks x 256 threads = 131072 threads = N_*HW_ pixels.
__global__ __launch_bounds__(256) void k_pw(
    const float* __restrict__ y, const float* __restrict__ stats,
    const float* __restrict__ gn_g, const float* __restrict__ gn_b,
    const float* __restrict__ W_in, const float* __restrict__ b_in,
    const float* __restrict__ W_outT, const float* __restrict__ b_out,
    const float* __restrict__ x, float* __restrict__ u) {
    int gidx = blockIdx.x * 256 + threadIdx.x;
    int n = gidx >> 12;            // block-uniform (16 blocks per n)
    int pix = gidx & 4095;
    int b = n >> 4, l = n & 15;

    // ---- load y row (64 floats) into regs
    float yn[64];
    const float* yrow = &y[(size_t)(n * 4096 + pix) * 64];
    #pragma unroll
    for (int c4 = 0; c4 < 16; ++c4) {
        float4 v = *(const float4*)&yrow[c4 * 4];
        yn[c4 * 4 + 0] = v.x; yn[c4 * 4 + 1] = v.y;
        yn[c4 * 4 + 2] = v.z; yn[c4 * 4 + 3] = v.w;
    }

    // ---- GN apply (stats + affine are wave-uniform scalars)
    #pragma unroll
    for (int gg = 0; gg < 4; ++gg) {
        float mean = stats[(n * 4 + gg) * 2];
        float rstd = stats[(n * 4 + gg) * 2 + 1];
        #pragma unroll
        for (int k = 0; k < 16; ++k) {
            int c = gg * 16 + k;
            yn[c] = (yn[c] - mean) * rstd * gn_g[c] + gn_b[c];
        }
    }

    // ---- u accumulator init with bias
    float uacc[64];
    #pragma unroll
    for (int j = 0; j < 64; ++j) uacc[j] = b_out[j];

    // ---- fused W_in + GLU + W_out: per output channel o of the GLU
    for (int o = 0; o < 64; ++o) {
        const float* w1 = &W_in[o * 64];          // x1 row (wave-uniform)
        const float* w2 = &W_in[(64 + o) * 64];   // x2 row
        float x1 = b_in[o], x2 = b_in[64 + o];
        #pragma unroll
        for (int c = 0; c < 64; ++c) {
            x1 += yn[c] * w1[c];
            x2 += yn[c] * w2[c];
        }
        float z = x1 / (1.f + __expf(-x2));
        const float* wo = &W_outT[o * 64];        // W_out column o, contiguous
        #pragma unroll
        for (int j = 0; j < 64; ++j) uacc[j] += z * wo[j];
    }

    // ---- residual add (coalesced per-j across lanes) + store
    #pragma unroll
    for (int j = 0; j < 64; ++j)
        uacc[j] += x[((size_t)(b * 64 + j) * 16 + l) * 4096 + pix];

    float* urow = &u[(size_t)(n * 4096 + pix) * 64];
    #pragma unroll
    for (int j4 = 0; j4 < 16; ++j4) {
        float4 st;
        st.x = uacc[j4 * 4 + 0]; st.y = uacc[j4 * 4 + 1];
        st.z = uacc[j4 * 4 + 2]; st.w = uacc[j4 * 4 + 3];
        *(float4*)&urow[j4 * 4] = st;
    }
}

// ---------------- LRU scan over l, output (B,C,L,H,W) ----------------
// grid: b*h = 128 blocks. block 256: lanes = w, thread holds 16 (c) states.
__global__ __launch_bounds__(256) void k_scan(
    const float* __restrict__ u, const float* __restrict__ lr_t,
    const float* __restrict__ li_t, const float* __restrict__ gm_t,
    const float* __restrict__ c_re, const float* __restrict__ c_im,
    const float* __restrict__ d_skip, float* __restrict__ out) {
    __shared__ float us[64][65];
    int tid = threadIdx.x;
    int b = blockIdx.x >> 6, h = blockIdx.x & 63;
    int w = tid & 63;
    int cg = tid >> 6;            // 0..3
    float hr[16] = {}, hi[16] = {};
    for (int l = 0; l < 16; ++l) {
        int n = b * 16 + l;
        const float* ub = &u[(n * 4096 + h * 64) * 64];
        for (int k = 0; k < 16; ++k) {
            int idx = k * 256 + tid;
            us[idx >> 6][idx & 63] = ub[idx];   // us[w][c]
        }
        __syncthreads();
        #pragma unroll
        for (int e = 0; e < 16; ++e) {
            int c = e * 4 + cg;
            float ut = us[w][c];
            float lr = lr_t[n * 64 + c], li = li_t[n * 64 + c], gm = gm_t[n * 64 + c];
            float nr = lr * hr[e] - li * hi[e] + gm * ut;
            float ni = li * hr[e] + lr * hi[e];
            float yv = c_re[c] * nr + c_im[c] * ni + d_skip[c] * ut;
            hr[e] = nr; hi[e] = ni;
            out[((b * 64 + c) * 16 + l) * 4096 + h * 64 + w] = yv;
        }
        __syncthreads();
    }
}

extern "C" void kernel_launch(void* const* d_in, const int* in_sizes, int n_in,
                              void* d_out, int out_size, void* d_ws, size_t ws_size,
                              hipStream_t stream) {
    const float* x        = (const float*)d_in[0];
    const float* dt       = (const float*)d_in[1];
    const float* W_sp     = (const float*)d_in[2];
    const float* W_dc     = (const float*)d_in[3];
    const float* b_dc     = (const float*)d_in[4];
    const float* gn_g     = (const float*)d_in[5];
    const float* gn_b     = (const float*)d_in[6];
    const float* W_in     = (const float*)d_in[7];
    const float* b_in     = (const float*)d_in[8];
    const float* W_out    = (const float*)d_in[9];
    const float* b_out    = (const float*)d_in[10];
    const float* nu_log   = (const float*)d_in[11];
    const float* theta_log= (const float*)d_in[12];
    const float* c_re     = (const float*)d_in[13];
    const float* c_im     = (const float*)d_in[14];
    const float* d_skip   = (const float*)d_in[15];

    float* ws    = (float*)d_ws;
    float* W_eff = ws + OFF_WEFF;
    float* y     = ws + OFF_Y;     // reused in-place as u by k_pw
    float* stats = ws + OFF_ST;
    float* lr_t  = ws + OFF_LR;
    float* li_t  = ws + OFF_LI;
    float* gm_t  = ws + OFF_GM;
    float* W_outT= ws + OFF_WOT;
    float* out   = (float*)d_out;

    hipLaunchKernelGGL(k_fold,    dim3(784),      dim3(256), 0, stream, W_sp, W_dc, W_eff);
    hipLaunchKernelGGL(k_wot,     dim3(16),       dim3(256), 0, stream, W_out, W_outT);
    hipLaunchKernelGGL(k_lam,     dim3(8),        dim3(256), 0, stream, dt, nu_log, theta_log, lr_t, li_t, gm_t);
    hipLaunchKernelGGL(k_conv,    dim3(16, 4, 32),dim3(256), 0, stream, x, W_eff, b_dc, y);
    hipLaunchKernelGGL(k_gnstats, dim3(128),      dim3(256), 0, stream, y, stats);
    hipLaunchKernelGGL(k_pw,      dim3(512),      dim3(256), 0, stream, y, stats, gn_g, gn_b,
                       W_in, b_in, W_outT, b_out, x, y);
    hipLaunchKernelGGL(k_scan,    dim3(128),      dim3(256), 0, stream, y, lr_t, li_t, gm_t,
                       c_re, c_im, d_skip, out);
}

// Round 3
// 571.252 us; speedup vs baseline: 2.8985x; 1.5537x over previous
//
#include <hip/hip_runtime.h>
#include <hip/hip_bf16.h>

typedef short bf16x8 __attribute__((ext_vector_type(8)));
typedef float f32x16 __attribute__((ext_vector_type(16)));

#define B_ 2
#define C_ 64
#define L_ 16
#define N_ 32
#define HW_ 4096

// ---- ws byte layout (total ~33.6 MB, < proven 34.4 MB capacity) ----
#define BY_WPH   0u          // packed weights hi: 49*512 frags * 16B = 802816
#define BY_WPL   802816u     // packed weights lo
#define BY_LR    1605632u    // lam_re  N_*C_ f32 = 8192
#define BY_LI    1613824u
#define BY_GM    1622016u
#define BY_STATS 1630208u    // 128*2 f32
#define BY_WOT   1631232u    // W_outT 64*64 f32 = 16384
#define BY_XHI   1647616u    // x hi plane  [n][pix][ic] bf16 = 16777216
#define BY_XLO   18424832u   // x lo plane
#define BY_U     1647616u    // u f32 [n][pix][c] = 33554432 (aliases XHI+XLO, used after conv)

__device__ __forceinline__ unsigned short f2bf(float v) {
    unsigned int u = __float_as_uint(v);
    unsigned int r = u + 0x7FFFu + ((u >> 16) & 1u);
    return (unsigned short)(r >> 16);
}
__device__ __forceinline__ float bf2f(unsigned short s) {
    return __uint_as_float(((unsigned int)s) << 16);
}

// ---------------- pack W_eff = W_dc @ W_sp into B-fragment layout, hi/lo ----------------
// frag idx = ((tap*2+nf)*4+ks)*64 + lane ; lane: oc=nf*32+(lane&31), ic=ks*16+(lane>>5)*8+e
__global__ void k_pack(const float* __restrict__ W_sp, const float* __restrict__ W_dc,
                       unsigned short* __restrict__ WpH, unsigned short* __restrict__ WpL) {
    int idx = blockIdx.x * 256 + threadIdx.x;
    if (idx >= 49 * 512) return;
    int lane = idx & 63;
    int ks   = (idx >> 6) & 3;
    int nf   = (idx >> 8) & 1;
    int tap  = idx >> 9;
    int oc   = nf * 32 + (lane & 31);
    int icb  = ks * 16 + (lane >> 5) * 8;
    unsigned short h8[8], l8[8];
    #pragma unroll
    for (int e = 0; e < 8; ++e) {
        int ic = icb + e;
        float s = 0.f;
        for (int c = 0; c < 64; ++c)
            s += W_dc[oc * 64 + c] * W_sp[(c * 64 + ic) * 49 + tap];
        unsigned short hb = f2bf(s);
        h8[e] = hb;
        l8[e] = f2bf(s - bf2f(hb));
    }
    #pragma unroll
    for (int e = 0; e < 8; ++e) { WpH[idx * 8 + e] = h8[e]; WpL[idx * 8 + e] = l8[e]; }
}

// ---------------- transpose W_out ----------------
__global__ void k_wot(const float* __restrict__ W_out, float* __restrict__ W_outT) {
    int idx = blockIdx.x * 256 + threadIdx.x;
    if (idx >= 64 * 64) return;
    int o = idx >> 6, j = idx & 63;
    W_outT[o * 64 + j] = W_out[j * 64 + o];
}

// ---------------- lambda tables ----------------
__global__ void k_lam(const float* __restrict__ dt, const float* __restrict__ nu_log,
                      const float* __restrict__ theta_log,
                      float* __restrict__ lr_t, float* __restrict__ li_t, float* __restrict__ gm_t) {
    int idx = blockIdx.x * 256 + threadIdx.x;
    if (idx >= N_ * C_) return;
    int c = idx & 63, n = idx >> 6;
    float dtv = dt[n];
    float decay = expf(-expf(nu_log[c]) * dtv);
    float phase = expf(theta_log[c]) * dtv;
    lr_t[idx] = decay * cosf(phase);
    li_t[idx] = decay * sinf(phase);
    gm_t[idx] = sqrtf(fmaxf(1.f - decay * decay, 1e-6f));
}

// ---------------- x transpose + bf16 split: xhi/xlo[n][pix][ic] ----------------
__global__ __launch_bounds__(256) void k_tr(const float* __restrict__ x,
                                            unsigned short* __restrict__ xhi,
                                            unsigned short* __restrict__ xlo) {
    __shared__ float t[64][129];
    int n = blockIdx.x >> 2, q = blockIdx.x & 3;
    int b = n >> 4, l = n & 15;
    int tid = threadIdx.x;
    for (int sub = 0; sub < 8; ++sub) {
        int p0 = q * 1024 + sub * 128;
        for (int i = 0; i < 32; ++i) {
            int idx = i * 256 + tid;
            int ic = idx >> 7, p = idx & 127;
            t[ic][p] = x[(((size_t)(b * 64 + ic) * 16 + l)) * 4096 + p0 + p];
        }
        __syncthreads();
        for (int it = 0; it < 4; ++it) {
            int chunk = it * 256 + tid;
            int p = chunk >> 3, c0 = (chunk & 7) * 8;
            unsigned short h8[8], l8[8];
            #pragma unroll
            for (int e = 0; e < 8; ++e) {
                float v = t[c0 + e][p];
                unsigned short hb = f2bf(v);
                h8[e] = hb;
                l8[e] = f2bf(v - bf2f(hb));
            }
            size_t off = ((size_t)(n * 4096 + p0 + p)) * 64 + c0;
            *(uint4*)&xhi[off] = *(uint4*)h8;
            *(uint4*)&xlo[off] = *(uint4*)l8;
        }
        __syncthreads();
    }
}

// ---------------- MFMA implicit-GEMM 7x7 conv ----------------
// block: 16x16 spatial tile x 64 oc, 4 waves (each 64 pix x 64 oc = 2x2 of 32x32 frags)
// LDS: 22x22 halo (padded to 488 rows) x 64 ic bf16, 128B rows, 16B-slot XOR swizzle
template<bool FIRST>
__device__ __forceinline__ void conv_pass(const unsigned short* __restrict__ xplane,
                                          const unsigned short* __restrict__ WpH,
                                          const unsigned short* __restrict__ WpL,
                                          uint4* halo, f32x16 (&acc)[2][2],
                                          int th, int tw, int n, int lane, int wid) {
    int dh = (lane >> 4) & 1, dw = lane & 15, kslot = lane >> 5;
    // ---- stage halo plane
    for (int u = wid; u < 61; u += 4) {
        int row = u * 8 + (lane >> 3);
        if (row > 483) row = 483;
        int hh = row / 22, ww = row - hh * 22;
        int hs = th * 16 + hh - 3; hs = hs < 0 ? 0 : (hs > 63 ? 63 : hs);
        int wv = (tw * 16 + ww - 3) & 63;
        const uint4* src = (const uint4*)(xplane + ((size_t)n * 4096 + hs * 64 + wv) * 64) + (lane & 7);
        uint4 v = *src;
        *(uint4*)((char*)halo + ((row << 7) + (((lane & 7) ^ (row & 7)) << 4))) = v;
    }
    __syncthreads();
    // ---- taps
    for (int kh = 0; kh < 7; ++kh) {
        for (int kw = 0; kw < 7; ++kw) {
            int tap = kh * 7 + kw;
            bf16x8 A[2][4];
            #pragma unroll
            for (int m = 0; m < 2; ++m) {
                int rowb = (wid * 4 + 2 * m + dh + kh) * 22 + dw + kw;
                #pragma unroll
                for (int ks = 0; ks < 4; ++ks) {
                    int byt = (rowb << 7) + (((2 * ks + kslot) ^ (rowb & 7)) << 4);
                    A[m][ks] = *(const bf16x8*)((const char*)halo + byt);
                }
            }
            const bf16x8* WH = (const bf16x8*)WpH + (size_t)tap * 512 + lane;
            const bf16x8* WL = (const bf16x8*)WpL + (size_t)tap * 512 + lane;
            bf16x8 Bh[2][4], Bl[2][4];
            #pragma unroll
            for (int nf = 0; nf < 2; ++nf)
                #pragma unroll
                for (int ks = 0; ks < 4; ++ks) {
                    Bh[nf][ks] = WH[(nf * 4 + ks) * 64];
                    if (FIRST) Bl[nf][ks] = WL[(nf * 4 + ks) * 64];
                }
            #pragma unroll
            for (int ks = 0; ks < 4; ++ks)
                #pragma unroll
                for (int m = 0; m < 2; ++m)
                    #pragma unroll
                    for (int nf = 0; nf < 2; ++nf) {
                        acc[m][nf] = __builtin_amdgcn_mfma_f32_32x32x16_bf16(A[m][ks], Bh[nf][ks], acc[m][nf], 0, 0, 0);
                        if (FIRST)
                            acc[m][nf] = __builtin_amdgcn_mfma_f32_32x32x16_bf16(A[m][ks], Bl[nf][ks], acc[m][nf], 0, 0, 0);
                    }
        }
    }
    __syncthreads();
}

__global__ __launch_bounds__(256, 2) void k_conv(
    const unsigned short* __restrict__ xhi, const unsigned short* __restrict__ xlo,
    const unsigned short* __restrict__ WpH, const unsigned short* __restrict__ WpL,
    const float* __restrict__ b_dc, float* __restrict__ y) {
    __shared__ uint4 halo[3904];   // 62464 B
    int tid = threadIdx.x;
    int tile = blockIdx.x;
    int th = tile >> 2, tw = tile & 3;
    int n = blockIdx.y;
    int lane = tid & 63, wid = tid >> 6;

    f32x16 acc[2][2] = {};
    conv_pass<true >(xhi, WpH, WpL, halo, acc, th, tw, n, lane, wid);
    conv_pass<false>(xlo, WpH, WpL, halo, acc, th, tw, n, lane, wid);

    // epilogue: C/D layout col=lane&31 (oc), row=(j&3)+8*(j>>2)+4*(lane>>5) (pixel)
    int ocl = lane & 31;
    #pragma unroll
    for (int nf = 0; nf < 2; ++nf) {
        float bv = b_dc[nf * 32 + ocl];
        #pragma unroll
        for (int m = 0; m < 2; ++m) {
            #pragma unroll
            for (int j = 0; j < 16; ++j) {
                int r = (j & 3) + 8 * (j >> 2) + 4 * (lane >> 5);
                int h = th * 16 + wid * 4 + 2 * m + (r >> 4);
                int w = tw * 16 + (r & 15);
                y[((size_t)n * 4096 + h * 64 + w) * 64 + nf * 32 + ocl] = acc[m][nf][j] + bv;
            }
        }
    }
}

// ---------------- GroupNorm stats per (n, g) ----------------
__global__ void k_gnstats(const float* __restrict__ y, float* __restrict__ stats) {
    int bid = blockIdx.x;
    int n = bid >> 2, g = bid & 3;
    int tid = threadIdx.x;
    int c = g * 16 + (tid & 15);
    float s = 0.f, s2 = 0.f;
    for (int p = (tid >> 4); p < 4096; p += 16) {
        float v = y[((size_t)n * 4096 + p) * 64 + c];
        s += v; s2 += v * v;
    }
    __shared__ float rs[256], rq[256];
    rs[tid] = s; rq[tid] = s2;
    __syncthreads();
    for (int off = 128; off; off >>= 1) {
        if (tid < off) { rs[tid] += rs[tid + off]; rq[tid] += rq[tid + off]; }
        __syncthreads();
    }
    if (tid == 0) {
        float mean = rs[0] * (1.f / 65536.f);
        float var  = rq[0] * (1.f / 65536.f) - mean * mean;
        stats[bid * 2]     = mean;
        stats[bid * 2 + 1] = rsqrtf(var + 1e-5f);
    }
}

// ---------------- GN-apply + W_in + GLU + W_out + residual ----------------
__global__ __launch_bounds__(256) void k_pw(
    const float* __restrict__ y, const float* __restrict__ stats,
    const float* __restrict__ gn_g, const float* __restrict__ gn_b,
    const float* __restrict__ W_in, const float* __restrict__ b_in,
    const float* __restrict__ W_outT, const float* __restrict__ b_out,
    const float* __restrict__ x, float* __restrict__ u) {
    int gidx = blockIdx.x * 256 + threadIdx.x;
    int n = gidx >> 12;
    int pix = gidx & 4095;
    int b = n >> 4, l = n & 15;

    float yn[64];
    const float* yrow = &y[(size_t)(n * 4096 + pix) * 64];
    #pragma unroll
    for (int c4 = 0; c4 < 16; ++c4) {
        float4 v = *(const float4*)&yrow[c4 * 4];
        yn[c4 * 4 + 0] = v.x; yn[c4 * 4 + 1] = v.y;
        yn[c4 * 4 + 2] = v.z; yn[c4 * 4 + 3] = v.w;
    }
    #pragma unroll
    for (int gg = 0; gg < 4; ++gg) {
        float mean = stats[(n * 4 + gg) * 2];
        float rstd = stats[(n * 4 + gg) * 2 + 1];
        #pragma unroll
        for (int k = 0; k < 16; ++k) {
            int c = gg * 16 + k;
            yn[c] = (yn[c] - mean) * rstd * gn_g[c] + gn_b[c];
        }
    }
    float uacc[64];
    #pragma unroll
    for (int j = 0; j < 64; ++j) uacc[j] = b_out[j];

    for (int o = 0; o < 64; ++o) {
        const float* w1 = &W_in[o * 64];
        const float* w2 = &W_in[(64 + o) * 64];
        float x1 = b_in[o], x2 = b_in[64 + o];
        #pragma unroll
        for (int c = 0; c < 64; ++c) {
            x1 += yn[c] * w1[c];
            x2 += yn[c] * w2[c];
        }
        float z = x1 / (1.f + __expf(-x2));
        const float* wo = &W_outT[o * 64];
        #pragma unroll
        for (int j = 0; j < 64; ++j) uacc[j] += z * wo[j];
    }
    #pragma unroll
    for (int j = 0; j < 64; ++j)
        uacc[j] += x[((size_t)(b * 64 + j) * 16 + l) * 4096 + pix];

    float* urow = &u[(size_t)(n * 4096 + pix) * 64];
    #pragma unroll
    for (int j4 = 0; j4 < 16; ++j4) {
        float4 st;
        st.x = uacc[j4 * 4 + 0]; st.y = uacc[j4 * 4 + 1];
        st.z = uacc[j4 * 4 + 2]; st.w = uacc[j4 * 4 + 3];
        *(float4*)&urow[j4 * 4] = st;
    }
}

// ---------------- LRU scan ----------------
__global__ __launch_bounds__(256) void k_scan(
    const float* __restrict__ u, const float* __restrict__ lr_t,
    const float* __restrict__ li_t, const float* __restrict__ gm_t,
    const float* __restrict__ c_re, const float* __restrict__ c_im,
    const float* __restrict__ d_skip, float* __restrict__ out) {
    __shared__ float us[64][65];
    int tid = threadIdx.x;
    int b = blockIdx.x >> 6, h = blockIdx.x & 63;
    int w = tid & 63;
    int cg = tid >> 6;
    float hr[16] = {}, hi[16] = {};
    for (int l = 0; l < 16; ++l) {
        int n = b * 16 + l;
        const float* ub = &u[((size_t)n * 4096 + h * 64) * 64];
        for (int k = 0; k < 16; ++k) {
            int idx = k * 256 + tid;
            us[idx >> 6][idx & 63] = ub[idx];
        }
        __syncthreads();
        #pragma unroll
        for (int e = 0; e < 16; ++e) {
            int c = e * 4 + cg;
            float ut = us[w][c];
            float lr = lr_t[n * 64 + c], li = li_t[n * 64 + c], gm = gm_t[n * 64 + c];
            float nr = lr * hr[e] - li * hi[e] + gm * ut;
            float ni = li * hr[e] + lr * hi[e];
            float yv = c_re[c] * nr + c_im[c] * ni + d_skip[c] * ut;
            hr[e] = nr; hi[e] = ni;
            out[((size_t)(b * 64 + c) * 16 + l) * 4096 + h * 64 + w] = yv;
        }
        __syncthreads();
    }
}

extern "C" void kernel_launch(void* const* d_in, const int* in_sizes, int n_in,
                              void* d_out, int out_size, void* d_ws, size_t ws_size,
                              hipStream_t stream) {
    const float* x        = (const float*)d_in[0];
    const float* dt       = (const float*)d_in[1];
    const float* W_sp     = (const float*)d_in[2];
    const float* W_dc     = (const float*)d_in[3];
    const float* b_dc     = (const float*)d_in[4];
    const float* gn_g     = (const float*)d_in[5];
    const float* gn_b     = (const float*)d_in[6];
    const float* W_in     = (const float*)d_in[7];
    const float* b_in     = (const float*)d_in[8];
    const float* W_out    = (const float*)d_in[9];
    const float* b_out    = (const float*)d_in[10];
    const float* nu_log   = (const float*)d_in[11];
    const float* theta_log= (const float*)d_in[12];
    const float* c_re     = (const float*)d_in[13];
    const float* c_im     = (const float*)d_in[14];
    const float* d_skip   = (const float*)d_in[15];

    char* ws = (char*)d_ws;
    unsigned short* WpH  = (unsigned short*)(ws + BY_WPH);
    unsigned short* WpL  = (unsigned short*)(ws + BY_WPL);
    float* lr_t   = (float*)(ws + BY_LR);
    float* li_t   = (float*)(ws + BY_LI);
    float* gm_t   = (float*)(ws + BY_GM);
    float* stats  = (float*)(ws + BY_STATS);
    float* W_outT = (float*)(ws + BY_WOT);
    unsigned short* xhi = (unsigned short*)(ws + BY_XHI);
    unsigned short* xlo = (unsigned short*)(ws + BY_XLO);
    float* u      = (float*)(ws + BY_U);
    float* y      = (float*)d_out;     // y lives in d_out until k_pw consumes it
    float* out    = (float*)d_out;

    hipLaunchKernelGGL(k_pack,    dim3(98),        dim3(256), 0, stream, W_sp, W_dc, WpH, WpL);
    hipLaunchKernelGGL(k_wot,     dim3(16),        dim3(256), 0, stream, W_out, W_outT);
    hipLaunchKernelGGL(k_lam,     dim3(8),         dim3(256), 0, stream, dt, nu_log, theta_log, lr_t, li_t, gm_t);
    hipLaunchKernelGGL(k_tr,      dim3(128),       dim3(256), 0, stream, x, xhi, xlo);
    hipLaunchKernelGGL(k_conv,    dim3(16, 32),    dim3(256), 0, stream, xhi, xlo, WpH, WpL, b_dc, y);
    hipLaunchKernelGGL(k_gnstats, dim3(128),       dim3(256), 0, stream, y, stats);
    hipLaunchKernelGGL(k_pw,      dim3(512),       dim3(256), 0, stream, y, stats, gn_g, gn_b,
                       W_in, b_in, W_outT, b_out, x, u);
    hipLaunchKernelGGL(k_scan,    dim3(128),       dim3(256), 0, stream, u, lr_t, li_t, gm_t,
                       c_re, c_im, d_skip, out);
}

// Round 4
// 380.924 us; speedup vs baseline: 4.3467x; 1.4996x over previous
//
#include <hip/hip_runtime.h>
#include <hip/hip_bf16.h>

typedef short bf16x8 __attribute__((ext_vector_type(8)));
typedef float f32x16 __attribute__((ext_vector_type(16)));

#define B_ 2
#define C_ 64
#define L_ 16
#define N_ 32
#define HW_ 4096

// ---- ws byte layout ----
#define BY_WPH   0u          // packed weights hi: 25088 frags * 16B = 401408
#define BY_WPL   401408u
#define BY_LR    802816u
#define BY_LI    811008u
#define BY_GM    819200u
#define BY_PART  827392u     // gn partial sums: 256 blocks * 8 f32
#define BY_WOT   835584u     // W_outT 64*64 f32
#define BY_XHI   851968u     // x bf16 plane [n][pix][ic] = 16777216
#define BY_U     851968u     // u f32 [n][pix][c] = 33554432 (aliases XHI, used after conv)

__device__ __forceinline__ unsigned short f2bf(float v) {
    unsigned int u = __float_as_uint(v);
    unsigned int r = u + 0x7FFFu + ((u >> 16) & 1u);
    return (unsigned short)(r >> 16);
}
__device__ __forceinline__ float bf2f(unsigned short s) {
    return __uint_as_float(((unsigned int)s) << 16);
}

// ---------------- pack W_eff = W_dc @ W_sp into B-fragment layout, hi/lo ----------------
// frag idx = ((tap*2+nf)*4+ks)*64 + lane ; lane: oc=nf*32+(lane&31), ic=ks*16+(lane>>5)*8+e
__global__ void k_pack(const float* __restrict__ W_sp, const float* __restrict__ W_dc,
                       unsigned short* __restrict__ WpH, unsigned short* __restrict__ WpL) {
    int idx = blockIdx.x * 256 + threadIdx.x;
    if (idx >= 49 * 512) return;
    int lane = idx & 63;
    int ks   = (idx >> 6) & 3;
    int nf   = (idx >> 8) & 1;
    int tap  = idx >> 9;
    int oc   = nf * 32 + (lane & 31);
    int icb  = ks * 16 + (lane >> 5) * 8;
    unsigned short h8[8], l8[8];
    #pragma unroll
    for (int e = 0; e < 8; ++e) {
        int ic = icb + e;
        float s = 0.f;
        for (int c = 0; c < 64; ++c)
            s += W_dc[oc * 64 + c] * W_sp[(c * 64 + ic) * 49 + tap];
        unsigned short hb = f2bf(s);
        h8[e] = hb;
        l8[e] = f2bf(s - bf2f(hb));
    }
    #pragma unroll
    for (int e = 0; e < 8; ++e) { WpH[idx * 8 + e] = h8[e]; WpL[idx * 8 + e] = l8[e]; }
}

// ---------------- transpose W_out ----------------
__global__ void k_wot(const float* __restrict__ W_out, float* __restrict__ W_outT) {
    int idx = blockIdx.x * 256 + threadIdx.x;
    if (idx >= 64 * 64) return;
    int o = idx >> 6, j = idx & 63;
    W_outT[o * 64 + j] = W_out[j * 64 + o];
}

// ---------------- lambda tables ----------------
__global__ void k_lam(const float* __restrict__ dt, const float* __restrict__ nu_log,
                      const float* __restrict__ theta_log,
                      float* __restrict__ lr_t, float* __restrict__ li_t, float* __restrict__ gm_t) {
    int idx = blockIdx.x * 256 + threadIdx.x;
    if (idx >= N_ * C_) return;
    int c = idx & 63, n = idx >> 6;
    float dtv = dt[n];
    float decay = expf(-expf(nu_log[c]) * dtv);
    float phase = expf(theta_log[c]) * dtv;
    lr_t[idx] = decay * cosf(phase);
    li_t[idx] = decay * sinf(phase);
    gm_t[idx] = sqrtf(fmaxf(1.f - decay * decay, 1e-6f));
}

// ---------------- x transpose to bf16 plane: xhi[n][pix][ic] ----------------
__global__ __launch_bounds__(256) void k_tr(const float* __restrict__ x,
                                            unsigned short* __restrict__ xhi) {
    __shared__ float t[64][129];
    int n = blockIdx.x >> 2, q = blockIdx.x & 3;
    int b = n >> 4, l = n & 15;
    int tid = threadIdx.x;
    for (int sub = 0; sub < 8; ++sub) {
        int p0 = q * 1024 + sub * 128;
        for (int i = 0; i < 32; ++i) {
            int idx = i * 256 + tid;
            int ic = idx >> 7, p = idx & 127;
            t[ic][p] = x[(((size_t)(b * 64 + ic) * 16 + l)) * 4096 + p0 + p];
        }
        __syncthreads();
        for (int it = 0; it < 4; ++it) {
            int chunk = it * 256 + tid;
            int p = chunk >> 3, c0 = (chunk & 7) * 8;
            unsigned short h8[8];
            #pragma unroll
            for (int e = 0; e < 8; ++e) h8[e] = f2bf(t[c0 + e][p]);
            size_t off = ((size_t)(n * 4096 + p0 + p)) * 64 + c0;
            *(uint4*)&xhi[off] = *(uint4*)h8;
        }
        __syncthreads();
    }
}

// ---------------- MFMA implicit-GEMM 7x7 conv (x bf16, w split hi/lo) ----------------
// block: 16x16 spatial tile x 64 oc, 4 waves (each 64 pix x 64 oc = 2x2 of 32x32 frags)
__global__ __launch_bounds__(256, 2) void k_conv(
    const unsigned short* __restrict__ xhi,
    const unsigned short* __restrict__ WpH, const unsigned short* __restrict__ WpL,
    const float* __restrict__ b_dc, float* __restrict__ y) {
    __shared__ uint4 halo[3904];   // 484 rows x 128B (+pad)
    int tid = threadIdx.x;
    int tile = blockIdx.x;
    int th = tile >> 2, tw = tile & 3;
    int n = blockIdx.y;
    int lane = tid & 63, wid = tid >> 6;
    int dh = (lane >> 4) & 1, dw = lane & 15, kslot = lane >> 5;

    f32x16 acc[2][2] = {};

    // ---- stage halo plane (484 rows of 64 ic bf16, 16B-slot XOR swizzle)
    for (int u = wid; u < 61; u += 4) {
        int row = u * 8 + (lane >> 3);
        if (row > 483) row = 483;
        int hh = row / 22, ww = row - hh * 22;
        int hs = th * 16 + hh - 3; hs = hs < 0 ? 0 : (hs > 63 ? 63 : hs);
        int wv = (tw * 16 + ww - 3) & 63;
        const uint4* src = (const uint4*)(xhi + ((size_t)n * 4096 + hs * 64 + wv) * 64) + (lane & 7);
        uint4 v = *src;
        *(uint4*)((char*)halo + ((row << 7) + (((lane & 7) ^ (row & 7)) << 4))) = v;
    }
    __syncthreads();

    // ---- 49 taps
    for (int kh = 0; kh < 7; ++kh) {
        #pragma unroll
        for (int kw = 0; kw < 7; ++kw) {
            int tap = kh * 7 + kw;
            bf16x8 A[2][4];
            #pragma unroll
            for (int m = 0; m < 2; ++m) {
                int rowb = (wid * 4 + 2 * m + dh + kh) * 22 + dw + kw;
                #pragma unroll
                for (int ks = 0; ks < 4; ++ks) {
                    int byt = (rowb << 7) + (((2 * ks + kslot) ^ (rowb & 7)) << 4);
                    A[m][ks] = *(const bf16x8*)((const char*)halo + byt);
                }
            }
            const bf16x8* WH = (const bf16x8*)WpH + (size_t)tap * 512 + lane;
            const bf16x8* WL = (const bf16x8*)WpL + (size_t)tap * 512 + lane;
            bf16x8 Bh[2][4], Bl[2][4];
            #pragma unroll
            for (int nf = 0; nf < 2; ++nf)
                #pragma unroll
                for (int ks = 0; ks < 4; ++ks) {
                    Bh[nf][ks] = WH[(nf * 4 + ks) * 64];
                    Bl[nf][ks] = WL[(nf * 4 + ks) * 64];
                }
            #pragma unroll
            for (int ks = 0; ks < 4; ++ks)
                #pragma unroll
                for (int m = 0; m < 2; ++m)
                    #pragma unroll
                    for (int nf = 0; nf < 2; ++nf) {
                        acc[m][nf] = __builtin_amdgcn_mfma_f32_32x32x16_bf16(A[m][ks], Bh[nf][ks], acc[m][nf], 0, 0, 0);
                        acc[m][nf] = __builtin_amdgcn_mfma_f32_32x32x16_bf16(A[m][ks], Bl[nf][ks], acc[m][nf], 0, 0, 0);
                    }
        }
    }

    // epilogue: C/D layout col=lane&31 (oc), row=(j&3)+8*(j>>2)+4*(lane>>5) (pixel)
    int ocl = lane & 31;
    #pragma unroll
    for (int nf = 0; nf < 2; ++nf) {
        float bv = b_dc[nf * 32 + ocl];
        #pragma unroll
        for (int m = 0; m < 2; ++m) {
            #pragma unroll
            for (int j = 0; j < 16; ++j) {
                int r = (j & 3) + 8 * (j >> 2) + 4 * (lane >> 5);
                int h = th * 16 + wid * 4 + 2 * m + (r >> 4);
                int w = tw * 16 + (r & 15);
                y[((size_t)n * 4096 + h * 64 + w) * 64 + nf * 32 + ocl] = acc[m][nf][j] + bv;
            }
        }
    }
}

// ---------------- GroupNorm partial sums per (n, chunk of 512 pixels) ----------------
__global__ __launch_bounds__(256) void k_gnstats(const float* __restrict__ y,
                                                 float* __restrict__ part) {
    int bid = blockIdx.x;          // n*8 + chunk
    int n = bid >> 3, chunk = bid & 7;
    int tid = threadIdx.x;
    int c4 = tid & 15, pl = tid >> 4;
    int g = c4 >> 2;
    float s = 0.f, s2 = 0.f;
    for (int i = 0; i < 32; ++i) {
        int p = chunk * 512 + i * 16 + pl;
        float4 v = *(const float4*)&y[((size_t)n * 4096 + p) * 64 + c4 * 4];
        s  += v.x + v.y + v.z + v.w;
        s2 += v.x * v.x + v.y * v.y + v.z * v.z + v.w * v.w;
    }
    __shared__ float rs[256], rq[256];
    int slot = g * 64 + pl * 4 + (c4 & 3);
    rs[slot] = s; rq[slot] = s2;
    __syncthreads();
    for (int off = 32; off >= 1; off >>= 1) {
        int g2 = tid >> 6, k = tid & 63;
        if (k < off) {
            rs[g2 * 64 + k] += rs[g2 * 64 + k + off];
            rq[g2 * 64 + k] += rq[g2 * 64 + k + off];
        }
        __syncthreads();
    }
    if (tid < 4) {
        part[bid * 8 + tid * 2]     = rs[tid * 64];
        part[bid * 8 + tid * 2 + 1] = rq[tid * 64];
    }
}

// ---------------- GN-apply + W_in + GLU + W_out + residual ----------------
__global__ __launch_bounds__(256) void k_pw(
    const float* __restrict__ y, const float* __restrict__ part,
    const float* __restrict__ gn_g, const float* __restrict__ gn_b,
    const float* __restrict__ W_in, const float* __restrict__ b_in,
    const float* __restrict__ W_outT, const float* __restrict__ b_out,
    const float* __restrict__ x, float* __restrict__ u) {
    int gidx = blockIdx.x * 256 + threadIdx.x;
    int n = gidx >> 12;
    int pix = gidx & 4095;
    int b = n >> 4, l = n & 15;

    float yn[64];
    const float* yrow = &y[(size_t)(n * 4096 + pix) * 64];
    #pragma unroll
    for (int c4 = 0; c4 < 16; ++c4) {
        float4 v = *(const float4*)&yrow[c4 * 4];
        yn[c4 * 4 + 0] = v.x; yn[c4 * 4 + 1] = v.y;
        yn[c4 * 4 + 2] = v.z; yn[c4 * 4 + 3] = v.w;
    }
    #pragma unroll
    for (int gg = 0; gg < 4; ++gg) {
        float sm = 0.f, sq = 0.f;
        #pragma unroll
        for (int ch = 0; ch < 8; ++ch) {
            sm += part[(n * 8 + ch) * 8 + gg * 2];
            sq += part[(n * 8 + ch) * 8 + gg * 2 + 1];
        }
        float mean = sm * (1.f / 65536.f);
        float var  = sq * (1.f / 65536.f) - mean * mean;
        float rstd = rsqrtf(var + 1e-5f);
        #pragma unroll
        for (int k = 0; k < 16; ++k) {
            int c = gg * 16 + k;
            yn[c] = (yn[c] - mean) * rstd * gn_g[c] + gn_b[c];
        }
    }
    float uacc[64];
    #pragma unroll
    for (int j = 0; j < 64; ++j) uacc[j] = b_out[j];

    for (int o = 0; o < 64; ++o) {
        const float* w1 = &W_in[o * 64];
        const float* w2 = &W_in[(64 + o) * 64];
        float x1 = b_in[o], x2 = b_in[64 + o];
        #pragma unroll
        for (int c = 0; c < 64; ++c) {
            x1 += yn[c] * w1[c];
            x2 += yn[c] * w2[c];
        }
        float z = x1 / (1.f + __expf(-x2));
        const float* wo = &W_outT[o * 64];
        #pragma unroll
        for (int j = 0; j < 64; ++j) uacc[j] += z * wo[j];
    }
    #pragma unroll
    for (int j = 0; j < 64; ++j)
        uacc[j] += x[((size_t)(b * 64 + j) * 16 + l) * 4096 + pix];

    float* urow = &u[(size_t)(n * 4096 + pix) * 64];
    #pragma unroll
    for (int j4 = 0; j4 < 16; ++j4) {
        float4 st;
        st.x = uacc[j4 * 4 + 0]; st.y = uacc[j4 * 4 + 1];
        st.z = uacc[j4 * 4 + 2]; st.w = uacc[j4 * 4 + 3];
        *(float4*)&urow[j4 * 4] = st;
    }
}

// ---------------- LRU scan: 512 blocks = (b, h, wq), coalesced float4 reads ----------------
__global__ __launch_bounds__(256) void k_scan(
    const float* __restrict__ u, const float* __restrict__ lr_t,
    const float* __restrict__ li_t, const float* __restrict__ gm_t,
    const float* __restrict__ c_re, const float* __restrict__ c_im,
    const float* __restrict__ d_skip, float* __restrict__ out) {
    __shared__ float us[16][68];
    int tid = threadIdx.x;
    int bid = blockIdx.x;
    int b = bid >> 8, h = (bid >> 2) & 63, wq = bid & 3;
    int c4 = tid & 15, p = tid >> 4;        // compute mapping: c_base = c4*4, w = wq*16+p
    int w = wq * 16 + p;
    float4 cr4 = *(const float4*)&c_re[c4 * 4];
    float4 ci4 = *(const float4*)&c_im[c4 * 4];
    float4 ds4 = *(const float4*)&d_skip[c4 * 4];
    float hr[4] = {}, hi[4] = {};
    int wp = tid & 15, cc = tid >> 4;       // write mapping
    for (int l = 0; l < 16; ++l) {
        int n = b * 16 + l;
        float4 uv = *(const float4*)&u[((size_t)(n * 4096 + h * 64 + w)) * 64 + c4 * 4];
        float4 lr4 = *(const float4*)&lr_t[n * 64 + c4 * 4];
        float4 li4 = *(const float4*)&li_t[n * 64 + c4 * 4];
        float4 gm4 = *(const float4*)&gm_t[n * 64 + c4 * 4];
        float yv[4];
        {
            float ut = uv.x, lr = lr4.x, li = li4.x;
            float nr = lr * hr[0] - li * hi[0] + gm4.x * ut;
            float ni = li * hr[0] + lr * hi[0];
            yv[0] = cr4.x * nr + ci4.x * ni + ds4.x * ut; hr[0] = nr; hi[0] = ni;
        }
        {
            float ut = uv.y, lr = lr4.y, li = li4.y;
            float nr = lr * hr[1] - li * hi[1] + gm4.y * ut;
            float ni = li * hr[1] + lr * hi[1];
            yv[1] = cr4.y * nr + ci4.y * ni + ds4.y * ut; hr[1] = nr; hi[1] = ni;
        }
        {
            float ut = uv.z, lr = lr4.z, li = li4.z;
            float nr = lr * hr[2] - li * hi[2] + gm4.z * ut;
            float ni = li * hr[2] + lr * hi[2];
            yv[2] = cr4.z * nr + ci4.z * ni + ds4.z * ut; hr[2] = nr; hi[2] = ni;
        }
        {
            float ut = uv.w, lr = lr4.w, li = li4.w;
            float nr = lr * hr[3] - li * hi[3] + gm4.w * ut;
            float ni = li * hr[3] + lr * hi[3];
            yv[3] = cr4.w * nr + ci4.w * ni + ds4.w * ut; hr[3] = nr; hi[3] = ni;
        }
        *(float4*)&us[p][c4 * 4] = *(float4*)yv;
        __syncthreads();
        #pragma unroll
        for (int j = 0; j < 4; ++j) {
            int c = cc * 4 + j;
            out[((size_t)(b * 64 + c) * 16 + l) * 4096 + h * 64 + wq * 16 + wp] = us[wp][c];
        }
        __syncthreads();
    }
}

extern "C" void kernel_launch(void* const* d_in, const int* in_sizes, int n_in,
                              void* d_out, int out_size, void* d_ws, size_t ws_size,
                              hipStream_t stream) {
    const float* x        = (const float*)d_in[0];
    const float* dt       = (const float*)d_in[1];
    const float* W_sp     = (const float*)d_in[2];
    const float* W_dc     = (const float*)d_in[3];
    const float* b_dc     = (const float*)d_in[4];
    const float* gn_g     = (const float*)d_in[5];
    const float* gn_b     = (const float*)d_in[6];
    const float* W_in     = (const float*)d_in[7];
    const float* b_in     = (const float*)d_in[8];
    const float* W_out    = (const float*)d_in[9];
    const float* b_out    = (const float*)d_in[10];
    const float* nu_log   = (const float*)d_in[11];
    const float* theta_log= (const float*)d_in[12];
    const float* c_re     = (const float*)d_in[13];
    const float* c_im     = (const float*)d_in[14];
    const float* d_skip   = (const float*)d_in[15];

    char* ws = (char*)d_ws;
    unsigned short* WpH  = (unsigned short*)(ws + BY_WPH);
    unsigned short* WpL  = (unsigned short*)(ws + BY_WPL);
    float* lr_t   = (float*)(ws + BY_LR);
    float* li_t   = (float*)(ws + BY_LI);
    float* gm_t   = (float*)(ws + BY_GM);
    float* part   = (float*)(ws + BY_PART);
    float* W_outT = (float*)(ws + BY_WOT);
    unsigned short* xhi = (unsigned short*)(ws + BY_XHI);
    float* u      = (float*)(ws + BY_U);
    float* y      = (float*)d_out;     // y lives in d_out until k_pw consumes it
    float* out    = (float*)d_out;

    hipLaunchKernelGGL(k_pack,    dim3(98),        dim3(256), 0, stream, W_sp, W_dc, WpH, WpL);
    hipLaunchKernelGGL(k_wot,     dim3(16),        dim3(256), 0, stream, W_out, W_outT);
    hipLaunchKernelGGL(k_lam,     dim3(8),         dim3(256), 0, stream, dt, nu_log, theta_log, lr_t, li_t, gm_t);
    hipLaunchKernelGGL(k_tr,      dim3(128),       dim3(256), 0, stream, x, xhi);
    hipLaunchKernelGGL(k_conv,    dim3(16, 32),    dim3(256), 0, stream, xhi, WpH, WpL, b_dc, y);
    hipLaunchKernelGGL(k_gnstats, dim3(256),       dim3(256), 0, stream, y, part);
    hipLaunchKernelGGL(k_pw,      dim3(512),       dim3(256), 0, stream, y, part, gn_g, gn_b,
                       W_in, b_in, W_outT, b_out, x, u);
    hipLaunchKernelGGL(k_scan,    dim3(512),       dim3(256), 0, stream, u, lr_t, li_t, gm_t,
                       c_re, c_im, d_skip, out);
}